// Round 1
// baseline (157.595 us; speedup 1.0000x reference)
//
#include <hip/hip_runtime.h>
#include <hip/hip_bf16.h>

#define LWAV   480000
#define XPADL  481024
#define NBATCH 32
#define TOUT   1000
#define MTOT   32000
#define NFFT   1024
#define NBINS  513
#define NMEL   64
#define PSTR   576
#define SPECW  1024
#define HOP    480

// workspace layout (bytes), all 256-aligned
#define XPAD_OFF 0u           // 32*481024*2      = 30,785,536
#define WB_OFF   30785536u    // 1026*1024*2      =  2,101,248
#define WMT_OFF  32886784u    // 64*576*2         =     73,728
#define PW_OFF   32960512u    // 32000*576*2      = 36,864,000
#define LM_OFF   69824512u    // 32000*64*4       =  8,192,000  -> total 78,016,512

typedef __attribute__((ext_vector_type(8))) __bf16 bf16x8;
typedef __attribute__((ext_vector_type(4))) float  f32x4;

__device__ __forceinline__ void gload16(const void* g, void* l) {
  __builtin_amdgcn_global_load_lds((const __attribute__((address_space(1))) void*)g,
                                   (__attribute__((address_space(3))) void*)l, 16, 0, 0);
}

// ---------------- prepass: bf16 conversions + reflect pad + filter transpose ----------------
__global__ void prep_kernel(const float* __restrict__ wav,
                            const float* __restrict__ wstft,
                            const float* __restrict__ mf,
                            unsigned char* __restrict__ ws) {
  __hip_bfloat16* xpad = (__hip_bfloat16*)(ws + XPAD_OFF);
  __hip_bfloat16* wb   = (__hip_bfloat16*)(ws + WB_OFF);
  __hip_bfloat16* wmt  = (__hip_bfloat16*)(ws + WMT_OFF);
  const long long N1 = (long long)NBATCH * XPADL;
  const long long N2 = 1026LL * NFFT;
  const long long N3 = (long long)NMEL * PSTR;
  long long idx = (long long)blockIdx.x * blockDim.x + threadIdx.x;
  if (idx >= N1 + N2 + N3) return;
  if (idx < N1) {
    int b = (int)(idx / XPADL);
    int p = (int)(idx - (long long)b * XPADL);
    int s = p - 512;
    if (s < 0) s = -s;
    else if (s >= LWAV) s = 2 * (LWAV - 1) - s;
    xpad[idx] = __float2bfloat16(wav[(long long)b * LWAV + s]);
  } else if (idx < N1 + N2) {
    long long j = idx - N1;
    wb[j] = __float2bfloat16(wstft[j]);
  } else {
    long long j = idx - N1 - N2;
    int n = (int)(j / PSTR);
    int k = (int)(j - (long long)n * PSTR);
    wmt[j] = __float2bfloat16(k < NBINS ? mf[k * NMEL + n] : 0.0f);
  }
}

// ---------------- STFT GEMM + power epilogue ----------------
// C[m][f] = frames[m][:] . W[f][:]  for cos rows f and sin rows 513+f, power = c^2+s^2
// block: BM=128 frames x 64 bins (128 weight rows), BK=64, 4 waves in 2x2
__launch_bounds__(256, 2)
__global__ void stft_kernel(unsigned char* __restrict__ ws) {
  __shared__ __align__(16) unsigned char sA[128 * 128];
  __shared__ __align__(16) unsigned char sB[128 * 128];
  const unsigned char* xpadb = ws + XPAD_OFF;
  const unsigned char* wbb   = ws + WB_OFF;
  __hip_bfloat16* pw = (__hip_bfloat16*)(ws + PW_OFF);

  const int tid = threadIdx.x;
  const int lane = tid & 63;
  const int wid  = tid >> 6;
  const int f0 = blockIdx.x * 64;
  const int m0 = blockIdx.y * 128;
  const int wm = (wid >> 1) * 64;
  const int wf = (wid & 1) * 32;

  const int srow = lane >> 3;          // 0..7: row within 8-row staging issue
  const int kb2  = (lane & 7) << 4;    // linear dest byte within 128B row

  const unsigned char* aptr[4];
  const unsigned char* bptr[4];
  unsigned char* aldst[4];
  unsigned char* bldst[4];
#pragma unroll
  for (int j = 0; j < 4; ++j) {
    int r = wid * 32 + j * 8 + srow;   // tile row 0..127
    int m = m0 + r;
    int bb = m / 1000;
    int t  = m - bb * 1000;
    // pre-swizzled global source (involution XOR on bits 4..6) -> linear LDS dest
    aptr[j] = xpadb + ((size_t)bb * XPADL + (size_t)t * HOP) * 2 + (kb2 ^ ((r & 7) << 4));
    aldst[j] = &sA[(wid * 32 + j * 8) * 128];
    int wr = (r < 64) ? (f0 + r) : (513 + f0 + (r - 64));
    if (wr > 1025) wr = 1025;          // clamp for the partial last f-tile
    bptr[j] = wbb + (size_t)wr * (NFFT * 2) + (kb2 ^ ((r & 7) << 4));
    bldst[j] = &sB[(wid * 32 + j * 8) * 128];
  }

  f32x4 accC[4][2], accS[4][2];
#pragma unroll
  for (int mi = 0; mi < 4; ++mi)
#pragma unroll
    for (int fr = 0; fr < 2; ++fr) {
      accC[mi][fr] = (f32x4){0.f, 0.f, 0.f, 0.f};
      accS[mi][fr] = (f32x4){0.f, 0.f, 0.f, 0.f};
    }

  for (int kk = 0; kk < NFFT; kk += 64) {
    __syncthreads();
#pragma unroll
    for (int j = 0; j < 4; ++j) gload16(aptr[j] + (size_t)kk * 2, aldst[j]);
#pragma unroll
    for (int j = 0; j < 4; ++j) gload16(bptr[j] + (size_t)kk * 2, bldst[j]);
    __syncthreads();
#pragma unroll
    for (int ks = 0; ks < 2; ++ks) {
      const int kby = ks * 64 + ((lane >> 4) << 4);
      bf16x8 af[4], bc[2], bs[2];
#pragma unroll
      for (int mi = 0; mi < 4; ++mi) {
        int r = wm + mi * 16 + (lane & 15);
        af[mi] = *(const bf16x8*)&sA[r * 128 + (kby ^ ((r & 7) << 4))];
      }
#pragma unroll
      for (int fr = 0; fr < 2; ++fr) {
        int rc = wf + fr * 16 + (lane & 15);
        int sw = kby ^ ((rc & 7) << 4);
        bc[fr] = *(const bf16x8*)&sB[rc * 128 + sw];
        bs[fr] = *(const bf16x8*)&sB[(64 + rc) * 128 + sw];
      }
#pragma unroll
      for (int mi = 0; mi < 4; ++mi)
#pragma unroll
        for (int fr = 0; fr < 2; ++fr) {
          accC[mi][fr] = __builtin_amdgcn_mfma_f32_16x16x32_bf16(af[mi], bc[fr], accC[mi][fr], 0, 0, 0);
          accS[mi][fr] = __builtin_amdgcn_mfma_f32_16x16x32_bf16(af[mi], bs[fr], accS[mi][fr], 0, 0, 0);
        }
    }
  }

  const int col = lane & 15;
  const int rg  = lane >> 4;
#pragma unroll
  for (int mi = 0; mi < 4; ++mi)
#pragma unroll
    for (int fr = 0; fr < 2; ++fr) {
      int f = f0 + wf + fr * 16 + col;   // < 576 always; pads written as 0
#pragma unroll
      for (int r = 0; r < 4; ++r) {
        int m = m0 + wm + mi * 16 + rg * 4 + r;
        float c = accC[mi][fr][r];
        float s = accS[mi][fr][r];
        float p = (f < NBINS) ? (c * c + s * s) : 0.0f;
        pw[(size_t)m * PSTR + f] = __float2bfloat16(p);
      }
    }
}

// ---------------- mel GEMM + log10 epilogue ----------------
// logmel[m][n] = 10*log10(max(sum_k pw[m][k]*filtT[n][k], 1e-10)); BM=128, N=64, K=576
__launch_bounds__(256, 2)
__global__ void mel_kernel(unsigned char* __restrict__ ws) {
  __shared__ __align__(16) unsigned char sA[128 * 128];
  __shared__ __align__(16) unsigned char sBt[64 * 128];
  const unsigned char* pwb  = ws + PW_OFF;
  const unsigned char* wmtb = ws + WMT_OFF;
  float* lm = (float*)(ws + LM_OFF);

  const int tid = threadIdx.x;
  const int lane = tid & 63;
  const int wid  = tid >> 6;
  const int m0 = blockIdx.x * 128;

  const int srow = lane >> 3;
  const int kb2  = (lane & 7) << 4;

  const unsigned char* aptr[4];
  unsigned char* aldst[4];
#pragma unroll
  for (int j = 0; j < 4; ++j) {
    int r = wid * 32 + j * 8 + srow;
    aptr[j] = pwb + (size_t)(m0 + r) * (PSTR * 2) + (kb2 ^ ((r & 7) << 4));
    aldst[j] = &sA[(wid * 32 + j * 8) * 128];
  }
  const unsigned char* bptr[2];
  unsigned char* bldst[2];
#pragma unroll
  for (int j = 0; j < 2; ++j) {
    int r = wid * 16 + j * 8 + srow;   // n row 0..63
    bptr[j] = wmtb + (size_t)r * (PSTR * 2) + (kb2 ^ ((r & 7) << 4));
    bldst[j] = &sBt[(wid * 16 + j * 8) * 128];
  }

  f32x4 acc[2][4];
#pragma unroll
  for (int mi = 0; mi < 2; ++mi)
#pragma unroll
    for (int fr = 0; fr < 4; ++fr) acc[mi][fr] = (f32x4){0.f, 0.f, 0.f, 0.f};

  for (int kk = 0; kk < PSTR; kk += 64) {
    __syncthreads();
#pragma unroll
    for (int j = 0; j < 4; ++j) gload16(aptr[j] + (size_t)kk * 2, aldst[j]);
#pragma unroll
    for (int j = 0; j < 2; ++j) gload16(bptr[j] + (size_t)kk * 2, bldst[j]);
    __syncthreads();
#pragma unroll
    for (int ks = 0; ks < 2; ++ks) {
      const int kby = ks * 64 + ((lane >> 4) << 4);
      bf16x8 af[2], bfr[4];
#pragma unroll
      for (int mi = 0; mi < 2; ++mi) {
        int r = wid * 32 + mi * 16 + (lane & 15);
        af[mi] = *(const bf16x8*)&sA[r * 128 + (kby ^ ((r & 7) << 4))];
      }
#pragma unroll
      for (int fr = 0; fr < 4; ++fr) {
        int r = fr * 16 + (lane & 15);
        bfr[fr] = *(const bf16x8*)&sBt[r * 128 + (kby ^ ((r & 7) << 4))];
      }
#pragma unroll
      for (int mi = 0; mi < 2; ++mi)
#pragma unroll
        for (int fr = 0; fr < 4; ++fr)
          acc[mi][fr] = __builtin_amdgcn_mfma_f32_16x16x32_bf16(af[mi], bfr[fr], acc[mi][fr], 0, 0, 0);
    }
  }

  const int col = lane & 15;
  const int rg  = lane >> 4;
#pragma unroll
  for (int mi = 0; mi < 2; ++mi)
#pragma unroll
    for (int fr = 0; fr < 4; ++fr) {
      int n = fr * 16 + col;
#pragma unroll
      for (int r = 0; r < 4; ++r) {
        int m = m0 + wid * 32 + mi * 16 + rg * 4 + r;
        float v = acc[mi][fr][r];
        lm[(size_t)m * NMEL + n] = 10.0f * log10f(fmaxf(v, 1e-10f));
      }
    }
}

// ---------------- bilinear (time-axis only) interp ----------------
__global__ void interp_kernel(const unsigned char* __restrict__ ws, float* __restrict__ out) {
  const float* lm = (const float*)(ws + LM_OFF);
  int idx = blockIdx.x * blockDim.x + threadIdx.x;  // b*16384 + h*16 + m4
  if (idx >= NBATCH * SPECW * 16) return;
  int m4 = idx & 15;
  int h  = (idx >> 4) & (SPECW - 1);
  int b  = idx >> 14;
  const float scale = (float)(999.0 / 1023.0);
  float pos = (float)h * scale;
  int i0 = (int)floorf(pos);
  if (i0 > TOUT - 1) i0 = TOUT - 1;
  float w = pos - (float)i0;
  int i1 = i0 + 1;
  if (i1 > TOUT - 1) i1 = TOUT - 1;
  const float4* r0 = (const float4*)(lm + ((size_t)b * TOUT + i0) * NMEL);
  const float4* r1 = (const float4*)(lm + ((size_t)b * TOUT + i1) * NMEL);
  float4 a = r0[m4], c = r1[m4];
  float4 o;
  o.x = a.x * (1.0f - w) + c.x * w;
  o.y = a.y * (1.0f - w) + c.y * w;
  o.z = a.z * (1.0f - w) + c.z * w;
  o.w = a.w * (1.0f - w) + c.w * w;
  ((float4*)out)[idx] = o;
}

extern "C" void kernel_launch(void* const* d_in, const int* in_sizes, int n_in,
                              void* d_out, int out_size, void* d_ws, size_t ws_size,
                              hipStream_t stream) {
  (void)in_sizes; (void)n_in; (void)out_size; (void)ws_size;
  const float* wav   = (const float*)d_in[0];
  const float* wstft = (const float*)d_in[1];
  const float* mf    = (const float*)d_in[2];
  unsigned char* ws  = (unsigned char*)d_ws;
  float* out = (float*)d_out;

  const long long tot = (long long)NBATCH * XPADL + 1026LL * NFFT + (long long)NMEL * PSTR;
  prep_kernel<<<(int)((tot + 255) / 256), 256, 0, stream>>>(wav, wstft, mf, ws);
  dim3 g1(9, 250);  // 9 f-tiles (64 bins each, covers 0..575) x 250 m-tiles
  stft_kernel<<<g1, 256, 0, stream>>>(ws);
  mel_kernel<<<250, 256, 0, stream>>>(ws);
  interp_kernel<<<(NBATCH * SPECW * 16) / 256, 256, 0, stream>>>(ws, out);
}

// Round 2
// 110.819 us; speedup vs baseline: 1.4221x; 1.4221x over previous
//
#include <hip/hip_runtime.h>
#include <hip/hip_bf16.h>

#define LWAV   480000
#define XPADL  481024
#define NBATCH 32
#define TOUT   1000
#define MTOT   32000
#define NFFT   1024
#define NBINS  513
#define NMEL   64
#define PSTR   576
#define SPECW  1024
#define HOP    480

// workspace layout (bytes), all 256-aligned
#define XPAD_OFF 0u           // 32*481024*2      = 30,785,536
#define WB_OFF   30785536u    // 1026*1024*2      =  2,101,248
#define WMT_OFF  32886784u    // 64*576*2         =     73,728
#define PW_OFF   32960512u    // 32000*576*2      = 36,864,000
#define LM_OFF   69824512u    // 32000*64*4       =  8,192,000  -> total 78,016,512

typedef __attribute__((ext_vector_type(8))) __bf16 bf16x8;
typedef __attribute__((ext_vector_type(4))) float  f32x4;

__device__ __forceinline__ void gload16(const void* g, void* l) {
  __builtin_amdgcn_global_load_lds((const __attribute__((address_space(1))) void*)g,
                                   (__attribute__((address_space(3))) void*)l, 16, 0, 0);
}

// ---------------- prepass: bf16 conversions + reflect pad + filter transpose ----------------
// vectorized: 8 elements / thread
#define NV1 (NBATCH * (XPADL / 8))          // 1,924,096
#define NV2 ((1026 * NFFT) / 8)             //   131,328
#define NV3 (NMEL * (PSTR / 8))             //     4,608

__global__ void prep_kernel(const float* __restrict__ wav,
                            const float* __restrict__ wstft,
                            const float* __restrict__ mf,
                            unsigned char* __restrict__ ws) {
  __hip_bfloat16* xpad = (__hip_bfloat16*)(ws + XPAD_OFF);
  __hip_bfloat16* wb   = (__hip_bfloat16*)(ws + WB_OFF);
  __hip_bfloat16* wmt  = (__hip_bfloat16*)(ws + WMT_OFF);
  int idx = blockIdx.x * blockDim.x + threadIdx.x;
  if (idx < NV1) {
    int b  = idx / (XPADL / 8);
    int pg = (idx - b * (XPADL / 8)) * 8;
    __hip_bfloat16* dst = xpad + (size_t)b * XPADL + pg;
    const float* src = wav + (size_t)b * LWAV;
    if (pg >= 512 && pg <= LWAV + 496) {   // fully-interior vector group
      float4 v0 = *(const float4*)(src + pg - 512);
      float4 v1 = *(const float4*)(src + pg - 508);
      __hip_bfloat16 t[8];
      t[0] = __float2bfloat16(v0.x); t[1] = __float2bfloat16(v0.y);
      t[2] = __float2bfloat16(v0.z); t[3] = __float2bfloat16(v0.w);
      t[4] = __float2bfloat16(v1.x); t[5] = __float2bfloat16(v1.y);
      t[6] = __float2bfloat16(v1.z); t[7] = __float2bfloat16(v1.w);
      *(uint4*)dst = *(const uint4*)t;
    } else {
      for (int j = 0; j < 8; ++j) {
        int s = pg + j - 512;
        if (s < 0) s = -s;
        else if (s >= LWAV) s = 2 * (LWAV - 1) - s;
        dst[j] = __float2bfloat16(src[s]);
      }
    }
  } else if (idx < NV1 + NV2) {
    int g = (idx - NV1) * 8;
    float4 v0 = *(const float4*)(wstft + g);
    float4 v1 = *(const float4*)(wstft + g + 4);
    __hip_bfloat16 t[8];
    t[0] = __float2bfloat16(v0.x); t[1] = __float2bfloat16(v0.y);
    t[2] = __float2bfloat16(v0.z); t[3] = __float2bfloat16(v0.w);
    t[4] = __float2bfloat16(v1.x); t[5] = __float2bfloat16(v1.y);
    t[6] = __float2bfloat16(v1.z); t[7] = __float2bfloat16(v1.w);
    *(uint4*)(wb + g) = *(const uint4*)t;
  } else if (idx < NV1 + NV2 + NV3) {
    int j  = idx - NV1 - NV2;
    int n  = j / (PSTR / 8);
    int k0 = (j - n * (PSTR / 8)) * 8;
    for (int k = k0; k < k0 + 8; ++k)
      wmt[n * PSTR + k] = __float2bfloat16(k < NBINS ? mf[k * NMEL + n] : 0.0f);
  }
}

// ---------------- STFT GEMM + power epilogue ----------------
// C[m][f] = frames[m][:] . W[f][:]  for cos rows f and sin rows 513+f, power = c^2+s^2
// block: BM=128 frames x 64 bins (128 weight rows), BK=64, 4 waves in 2x2
// grid: flattened 2250 with XCD-chunked bijective swizzle (T1/m204) so the 9
// f-tiles sharing one A m-panel are consecutive work-ids on ONE XCD's L2.
#define STFT_NWG (9 * 250)
__launch_bounds__(256, 2)
__global__ void stft_kernel(unsigned char* __restrict__ ws) {
  __shared__ __align__(16) unsigned char sA[128 * 128];
  __shared__ __align__(16) unsigned char sB[128 * 128];
  const unsigned char* xpadb = ws + XPAD_OFF;
  const unsigned char* wbb   = ws + WB_OFF;
  __hip_bfloat16* pw = (__hip_bfloat16*)(ws + PW_OFF);

  const int tid = threadIdx.x;
  const int lane = tid & 63;
  const int wid  = tid >> 6;

  // bijective XCD-chunked swizzle: nwg=2250, q=281, r=2
  const int orig = blockIdx.x;
  const int q = STFT_NWG / 8, r = STFT_NWG % 8;
  const int xcd = orig & 7;
  const int w = (xcd < r ? xcd * (q + 1) : r * (q + 1) + (xcd - r) * q) + (orig >> 3);
  const int f0 = (w % 9) * 64;
  const int m0 = (w / 9) * 128;

  const int wm = (wid >> 1) * 64;
  const int wf = (wid & 1) * 32;

  const int srow = lane >> 3;          // 0..7: row within 8-row staging issue
  const int kb2  = (lane & 7) << 4;    // linear dest byte within 128B row

  const unsigned char* aptr[4];
  const unsigned char* bptr[4];
  unsigned char* aldst[4];
  unsigned char* bldst[4];
#pragma unroll
  for (int j = 0; j < 4; ++j) {
    int rr = wid * 32 + j * 8 + srow;  // tile row 0..127
    int m = m0 + rr;
    int bb = m / 1000;
    int t  = m - bb * 1000;
    // pre-swizzled global source (involution XOR on bits 4..6) -> linear LDS dest
    aptr[j] = xpadb + ((size_t)bb * XPADL + (size_t)t * HOP) * 2 + (kb2 ^ ((rr & 7) << 4));
    aldst[j] = &sA[(wid * 32 + j * 8) * 128];
    int wr = (rr < 64) ? (f0 + rr) : (513 + f0 + (rr - 64));
    if (wr > 1025) wr = 1025;          // clamp for the partial last f-tile
    bptr[j] = wbb + (size_t)wr * (NFFT * 2) + (kb2 ^ ((rr & 7) << 4));
    bldst[j] = &sB[(wid * 32 + j * 8) * 128];
  }

  f32x4 accC[4][2], accS[4][2];
#pragma unroll
  for (int mi = 0; mi < 4; ++mi)
#pragma unroll
    for (int fr = 0; fr < 2; ++fr) {
      accC[mi][fr] = (f32x4){0.f, 0.f, 0.f, 0.f};
      accS[mi][fr] = (f32x4){0.f, 0.f, 0.f, 0.f};
    }

  for (int kk = 0; kk < NFFT; kk += 64) {
    __syncthreads();
#pragma unroll
    for (int j = 0; j < 4; ++j) gload16(aptr[j] + (size_t)kk * 2, aldst[j]);
#pragma unroll
    for (int j = 0; j < 4; ++j) gload16(bptr[j] + (size_t)kk * 2, bldst[j]);
    __syncthreads();
#pragma unroll
    for (int ks = 0; ks < 2; ++ks) {
      const int kby = ks * 64 + ((lane >> 4) << 4);
      bf16x8 af[4], bc[2], bs[2];
#pragma unroll
      for (int mi = 0; mi < 4; ++mi) {
        int rr = wm + mi * 16 + (lane & 15);
        af[mi] = *(const bf16x8*)&sA[rr * 128 + (kby ^ ((rr & 7) << 4))];
      }
#pragma unroll
      for (int fr = 0; fr < 2; ++fr) {
        int rc = wf + fr * 16 + (lane & 15);
        int sw = kby ^ ((rc & 7) << 4);
        bc[fr] = *(const bf16x8*)&sB[rc * 128 + sw];
        bs[fr] = *(const bf16x8*)&sB[(64 + rc) * 128 + sw];
      }
#pragma unroll
      for (int mi = 0; mi < 4; ++mi)
#pragma unroll
        for (int fr = 0; fr < 2; ++fr) {
          accC[mi][fr] = __builtin_amdgcn_mfma_f32_16x16x32_bf16(af[mi], bc[fr], accC[mi][fr], 0, 0, 0);
          accS[mi][fr] = __builtin_amdgcn_mfma_f32_16x16x32_bf16(af[mi], bs[fr], accS[mi][fr], 0, 0, 0);
        }
    }
  }

  const int col = lane & 15;
  const int rg  = lane >> 4;
#pragma unroll
  for (int mi = 0; mi < 4; ++mi)
#pragma unroll
    for (int fr = 0; fr < 2; ++fr) {
      int f = f0 + wf + fr * 16 + col;   // < 576 always; pads written as 0
#pragma unroll
      for (int rr = 0; rr < 4; ++rr) {
        int m = m0 + wm + mi * 16 + rg * 4 + rr;
        float c = accC[mi][fr][rr];
        float s = accS[mi][fr][rr];
        float p = (f < NBINS) ? (c * c + s * s) : 0.0f;
        pw[(size_t)m * PSTR + f] = __float2bfloat16(p);
      }
    }
}

// ---------------- mel GEMM + log10 epilogue ----------------
// logmel[m][n] = 10*log10(max(sum_k pw[m][k]*filtT[n][k], 1e-10)); BM=128, N=64, K=576
__launch_bounds__(256, 2)
__global__ void mel_kernel(unsigned char* __restrict__ ws) {
  __shared__ __align__(16) unsigned char sA[128 * 128];
  __shared__ __align__(16) unsigned char sBt[64 * 128];
  const unsigned char* pwb  = ws + PW_OFF;
  const unsigned char* wmtb = ws + WMT_OFF;
  float* lm = (float*)(ws + LM_OFF);

  const int tid = threadIdx.x;
  const int lane = tid & 63;
  const int wid  = tid >> 6;
  const int m0 = blockIdx.x * 128;

  const int srow = lane >> 3;
  const int kb2  = (lane & 7) << 4;

  const unsigned char* aptr[4];
  unsigned char* aldst[4];
#pragma unroll
  for (int j = 0; j < 4; ++j) {
    int rr = wid * 32 + j * 8 + srow;
    aptr[j] = pwb + (size_t)(m0 + rr) * (PSTR * 2) + (kb2 ^ ((rr & 7) << 4));
    aldst[j] = &sA[(wid * 32 + j * 8) * 128];
  }
  const unsigned char* bptr[2];
  unsigned char* bldst[2];
#pragma unroll
  for (int j = 0; j < 2; ++j) {
    int rr = wid * 16 + j * 8 + srow;   // n row 0..63
    bptr[j] = wmtb + (size_t)rr * (PSTR * 2) + (kb2 ^ ((rr & 7) << 4));
    bldst[j] = &sBt[(wid * 16 + j * 8) * 128];
  }

  f32x4 acc[2][4];
#pragma unroll
  for (int mi = 0; mi < 2; ++mi)
#pragma unroll
    for (int fr = 0; fr < 4; ++fr) acc[mi][fr] = (f32x4){0.f, 0.f, 0.f, 0.f};

  for (int kk = 0; kk < PSTR; kk += 64) {
    __syncthreads();
#pragma unroll
    for (int j = 0; j < 4; ++j) gload16(aptr[j] + (size_t)kk * 2, aldst[j]);
#pragma unroll
    for (int j = 0; j < 2; ++j) gload16(bptr[j] + (size_t)kk * 2, bldst[j]);
    __syncthreads();
#pragma unroll
    for (int ks = 0; ks < 2; ++ks) {
      const int kby = ks * 64 + ((lane >> 4) << 4);
      bf16x8 af[2], bfr[4];
#pragma unroll
      for (int mi = 0; mi < 2; ++mi) {
        int rr = wid * 32 + mi * 16 + (lane & 15);
        af[mi] = *(const bf16x8*)&sA[rr * 128 + (kby ^ ((rr & 7) << 4))];
      }
#pragma unroll
      for (int fr = 0; fr < 4; ++fr) {
        int rr = fr * 16 + (lane & 15);
        bfr[fr] = *(const bf16x8*)&sBt[rr * 128 + (kby ^ ((rr & 7) << 4))];
      }
#pragma unroll
      for (int mi = 0; mi < 2; ++mi)
#pragma unroll
        for (int fr = 0; fr < 4; ++fr)
          acc[mi][fr] = __builtin_amdgcn_mfma_f32_16x16x32_bf16(af[mi], bfr[fr], acc[mi][fr], 0, 0, 0);
    }
  }

  const int col = lane & 15;
  const int rg  = lane >> 4;
#pragma unroll
  for (int mi = 0; mi < 2; ++mi)
#pragma unroll
    for (int fr = 0; fr < 4; ++fr) {
      int n = fr * 16 + col;
#pragma unroll
      for (int rr = 0; rr < 4; ++rr) {
        int m = m0 + wid * 32 + mi * 16 + rg * 4 + rr;
        float v = acc[mi][fr][rr];
        lm[(size_t)m * NMEL + n] = 10.0f * log10f(fmaxf(v, 1e-10f));
      }
    }
}

// ---------------- bilinear (time-axis only) interp ----------------
__global__ void interp_kernel(const unsigned char* __restrict__ ws, float* __restrict__ out) {
  const float* lm = (const float*)(ws + LM_OFF);
  int idx = blockIdx.x * blockDim.x + threadIdx.x;  // b*16384 + h*16 + m4
  if (idx >= NBATCH * SPECW * 16) return;
  int m4 = idx & 15;
  int h  = (idx >> 4) & (SPECW - 1);
  int b  = idx >> 14;
  const float scale = (float)(999.0 / 1023.0);
  float pos = (float)h * scale;
  int i0 = (int)floorf(pos);
  if (i0 > TOUT - 1) i0 = TOUT - 1;
  float w = pos - (float)i0;
  int i1 = i0 + 1;
  if (i1 > TOUT - 1) i1 = TOUT - 1;
  const float4* r0 = (const float4*)(lm + ((size_t)b * TOUT + i0) * NMEL);
  const float4* r1 = (const float4*)(lm + ((size_t)b * TOUT + i1) * NMEL);
  float4 a = r0[m4], c = r1[m4];
  float4 o;
  o.x = a.x * (1.0f - w) + c.x * w;
  o.y = a.y * (1.0f - w) + c.y * w;
  o.z = a.z * (1.0f - w) + c.z * w;
  o.w = a.w * (1.0f - w) + c.w * w;
  ((float4*)out)[idx] = o;
}

extern "C" void kernel_launch(void* const* d_in, const int* in_sizes, int n_in,
                              void* d_out, int out_size, void* d_ws, size_t ws_size,
                              hipStream_t stream) {
  (void)in_sizes; (void)n_in; (void)out_size; (void)ws_size;
  const float* wav   = (const float*)d_in[0];
  const float* wstft = (const float*)d_in[1];
  const float* mf    = (const float*)d_in[2];
  unsigned char* ws  = (unsigned char*)d_ws;
  float* out = (float*)d_out;

  const int tot = NV1 + NV2 + NV3;
  prep_kernel<<<(tot + 255) / 256, 256, 0, stream>>>(wav, wstft, mf, ws);
  stft_kernel<<<STFT_NWG, 256, 0, stream>>>(ws);
  mel_kernel<<<250, 256, 0, stream>>>(ws);
  interp_kernel<<<(NBATCH * SPECW * 16) / 256, 256, 0, stream>>>(ws, out);
}